// Round 10
// baseline (45.726 us; speedup 1.0000x reference)
//
#include <hip/hip_runtime.h>

#define IMG    512
#define BAND   4            // output rows per wave
#define NBANDS 2048         // 16 images x 128 bands
#define NBLK   512          // 4 waves per block
#define NPIX   (16.0 * 512.0 * 512.0)
#define EPS    1e-5f
#define INV81  (1.0f / 81.0f)

struct Rows { float4 i0, i1, j0, j1; };

__device__ __forceinline__ Rows load_rows(const float* __restrict__ Ib,
                                          const float* __restrict__ Jb,
                                          int y, int col0)
{
    Rows r;
    if (y >= 0 && y < IMG) {          // wave-uniform (y uniform per wave)
        const float* rI = Ib + (size_t)y * IMG + col0;
        const float* rJ = Jb + (size_t)y * IMG + col0;
        r.i0 = *(const float4*)(rI);
        r.i1 = *(const float4*)(rI + 4);
        r.j0 = *(const float4*)(rJ);
        r.j1 = *(const float4*)(rJ + 4);
    } else {
        r.i0 = r.i1 = r.j0 = r.j1 = float4{0.f, 0.f, 0.f, 0.f};
    }
    return r;
}

#define ACC(c, xv, yv)                          \
    sI[c]  += (xv); sJ[c] += (yv);              \
    sII[c]  = fmaf((xv), (xv), sII[c]);         \
    sJJ[c]  = fmaf((yv), (yv), sJJ[c]);         \
    sIJ[c]  = fmaf((xv), (yv), sIJ[c]);

#define UPD(c, nx, ny, ox, oy)                                  \
    sI[c]  += (nx) - (ox);                                      \
    sJ[c]  += (ny) - (oy);                                      \
    sII[c]  = fmaf((nx), (nx), fmaf(-(ox), (ox), sII[c]));      \
    sJJ[c]  = fmaf((ny), (ny), fmaf(-(oy), (oy), sJJ[c]));      \
    sIJ[c]  = fmaf((nx), (ny), fmaf(-(ox), (oy), sIJ[c]));

// NOTE: parameter must NOT be named `w` — the body's `.w` member accesses
// would be macro-substituted (round 4's compile failure).
#define ACC_ROWS(R)                              \
    ACC(0, R.i0.x, R.j0.x) ACC(1, R.i0.y, R.j0.y)\
    ACC(2, R.i0.z, R.j0.z) ACC(3, R.i0.w, R.j0.w)\
    ACC(4, R.i1.x, R.j1.x) ACC(5, R.i1.y, R.j1.y)\
    ACC(6, R.i1.z, R.j1.z) ACC(7, R.i1.w, R.j1.w)

#define UPD_ROWS(NR, OR)                                                  \
    UPD(0, NR.i0.x, NR.j0.x, OR.i0.x, OR.j0.x)                            \
    UPD(1, NR.i0.y, NR.j0.y, OR.i0.y, OR.j0.y)                            \
    UPD(2, NR.i0.z, NR.j0.z, OR.i0.z, OR.j0.z)                            \
    UPD(3, NR.i0.w, NR.j0.w, OR.i0.w, OR.j0.w)                            \
    UPD(4, NR.i1.x, NR.j1.x, OR.i1.x, OR.j1.x)                            \
    UPD(5, NR.i1.y, NR.j1.y, OR.i1.y, OR.j1.y)                            \
    UPD(6, NR.i1.z, NR.j1.z, OR.i1.z, OR.j1.z)                            \
    UPD(7, NR.i1.w, NR.j1.w, OR.i1.w, OR.j1.w)

// Horizontal 9-window over one quantity's 8 column-sums.
// Halo column-sums come from neighbor lanes; lane 0/63 masked = zero pad.
__device__ __forceinline__ void hwin(const float s[8], int lane, float w[8])
{
    float l[4], r[4];
    #pragma unroll
    for (int i = 0; i < 4; ++i) {
        float lv = __shfl_up(s[4 + i], 1, 64);
        float rv = __shfl_down(s[i],   1, 64);
        l[i] = (lane == 0)  ? 0.f : lv;
        r[i] = (lane == 63) ? 0.f : rv;
    }
    w[0] = ((l[0] + l[1]) + (l[2] + l[3])) +
           ((s[0] + s[1]) + (s[2] + s[3])) + s[4];
    w[1] = w[0] + s[5] - l[0];
    w[2] = w[1] + s[6] - l[1];
    w[3] = w[2] + s[7] - l[2];
    w[4] = w[3] + r[0] - l[3];
    w[5] = w[4] + r[1] - s[0];
    w[6] = w[5] + r[2] - s[1];
    w[7] = w[6] + r[3] - s[2];
}

// One wave = one 4-row band (measured-best config). Fused finalize via
// last-block-done counter: works for ANY initial counter value (each call
// adds exactly NBLK, so exactly one block sees old%NBLK==NBLK-1) -> no
// init dispatch, deterministic across graph replays. Cross-XCD visibility
// via agent-scope atomics (per-XCD L2s are not coherent). No cooperative
// launch (round 8: silently fails in this harness). No launch_bounds
// min-wave arg (round 5: (256,4) forces 64 VGPR + catastrophic spill).
__global__ __launch_bounds__(256) void ncc_band_kernel(
    const float* __restrict__ I, const float* __restrict__ J,
    double* __restrict__ slots, unsigned int* __restrict__ counter,
    float* __restrict__ out)
{
    const int lane = threadIdx.x & 63;
    const int wid  = threadIdx.x >> 6;
    // bijective XCD swizzle over 512 blocks (512 % 8 == 0):
    // XCD k gets a contiguous 256-band chunk (2 images ~ its 4MB L2).
    const int sblk = (blockIdx.x & 7) * (NBLK / 8) + (blockIdx.x >> 3);
    const int band = sblk * 4 + wid;              // 0..2047
    const int img  = band >> 7;                   // 128 bands / image
    const int y0   = (band & 127) * BAND;
    const int col0 = lane * 8;

    const float* Ib = I + (size_t)img * IMG * IMG;
    const float* Jb = J + (size_t)img * IMG * IMG;

    float sI[8], sJ[8], sII[8], sJJ[8], sIJ[8];
    #pragma unroll
    for (int c = 0; c < 8; ++c) { sI[c]=0.f; sJ[c]=0.f; sII[c]=0.f; sJJ[c]=0.f; sIJ[c]=0.f; }

    // ---- warm-up: rows y0-4 .. y0+4 (rolled; caps live registers) ----
    for (int r = -4; r <= 4; ++r) {
        Rows rr = load_rows(Ib, Jb, y0 + r, col0);
        ACC_ROWS(rr)
    }

    float local = 0.0f;

    // lean hpass: one shared transient, wI/wJ reused for Iv/Jv
    auto hpass = [&]() {
        float wI[8], wJ[8], t[8], cross[8];
        hwin(sI, lane, wI);
        hwin(sJ, lane, wJ);
        hwin(sIJ, lane, t);
        #pragma unroll
        for (int k = 0; k < 8; ++k)
            cross[k] = fmaxf(fmaf(-wI[k] * INV81, wJ[k], t[k]), EPS);
        hwin(sII, lane, t);
        #pragma unroll
        for (int k = 0; k < 8; ++k)
            wI[k] = fmaxf(fmaf(-wI[k] * INV81, wI[k], t[k]), EPS);   // Iv
        hwin(sJJ, lane, t);
        #pragma unroll
        for (int k = 0; k < 8; ++k)
            wJ[k] = fmaxf(fmaf(-wJ[k] * INV81, wJ[k], t[k]), EPS);   // Jv
        #pragma unroll
        for (int k = 0; k < 8; ++k)
            local += (cross[k] * cross[k]) * __builtin_amdgcn_rcpf(wI[k] * wJ[k]);
    };

    // ---- main loop: 4 output rows, transitions t=0..2
    //      (new = y0+5+t, old = y0-4+t), loads issued >=1 hpass ahead ----
    Rows nw0 = load_rows(Ib, Jb, y0 + 5, col0);
    Rows od0 = load_rows(Ib, Jb, y0 - 4, col0);
    Rows nw1 = load_rows(Ib, Jb, y0 + 6, col0);
    Rows od1 = load_rows(Ib, Jb, y0 - 3, col0);

    hpass();                               // row y0
    UPD_ROWS(nw0, od0)
    nw0 = load_rows(Ib, Jb, y0 + 7, col0);
    od0 = load_rows(Ib, Jb, y0 - 2, col0);
    hpass();                               // row y0+1
    UPD_ROWS(nw1, od1)
    hpass();                               // row y0+2
    UPD_ROWS(nw0, od0)
    hpass();                               // row y0+3

    // ---- wave reduction -> per-wave slot (agent-scope release) ----
    #pragma unroll
    for (int off = 32; off > 0; off >>= 1)
        local += __shfl_down(local, off, 64);
    if (lane == 0)
        __hip_atomic_store(&slots[band], (double)local,
                           __ATOMIC_RELEASE, __HIP_MEMORY_SCOPE_AGENT);

    __syncthreads();                       // all 4 waves' stores issued

    __shared__ bool amLast;
    if (threadIdx.x == 0) {
        __threadfence();
        unsigned int old = __hip_atomic_fetch_add(
            counter, 1u, __ATOMIC_ACQ_REL, __HIP_MEMORY_SCOPE_AGENT);
        amLast = ((old % NBLK) == NBLK - 1);
    }
    __syncthreads();

    // ---- last block to finish reduces all slots ----
    if (amLast) {
        const int tid = threadIdx.x;
        double t = 0.0;
        #pragma unroll
        for (int i = 0; i < NBANDS / 256; ++i)
            t += __hip_atomic_load(&slots[tid + i * 256],
                                   __ATOMIC_ACQUIRE, __HIP_MEMORY_SCOPE_AGENT);
        #pragma unroll
        for (int off = 32; off > 0; off >>= 1)
            t += __shfl_down(t, off, 64);

        __shared__ double wsum[4];
        if ((tid & 63) == 0) wsum[tid >> 6] = t;
        __syncthreads();
        if (tid == 0)
            out[0] = (float)(-(wsum[0] + wsum[1] + wsum[2] + wsum[3]) / NPIX);
    }
}

extern "C" void kernel_launch(void* const* d_in, const int* in_sizes, int n_in,
                              void* d_out, int out_size, void* d_ws, size_t ws_size,
                              hipStream_t stream)
{
    const float* I = (const float*)d_in[0];   // y_true
    const float* J = (const float*)d_in[1];   // y_pred
    float* out = (float*)d_out;
    double* slots = (double*)d_ws;                 // 2048 doubles
    unsigned int* counter = (unsigned int*)(slots + NBANDS);  // next 4 bytes

    // single dispatch: 512 blocks x 256 threads
    ncc_band_kernel<<<NBLK, 256, 0, stream>>>(I, J, slots, counter, out);
}

// Round 12
// 19.267 us; speedup vs baseline: 2.3733x; 2.3733x over previous
//
#include <hip/hip_runtime.h>

#define IMG    512
#define BAND   4            // output rows per wave
#define NBANDS 2048         // 16 images x 128 bands
#define NBLK   512          // 4 waves per block
#define NPIX   (16.0 * 512.0 * 512.0)
#define EPS    1e-5f
#define INV81  (1.0f / 81.0f)

struct Rows { float4 i0, i1, j0, j1; };

__device__ __forceinline__ Rows load_rows(const float* __restrict__ Ib,
                                          const float* __restrict__ Jb,
                                          int y, int col0)
{
    Rows r;
    if (y >= 0 && y < IMG) {          // wave-uniform (y uniform per wave)
        const float* rI = Ib + (size_t)y * IMG + col0;
        const float* rJ = Jb + (size_t)y * IMG + col0;
        r.i0 = *(const float4*)(rI);
        r.i1 = *(const float4*)(rI + 4);
        r.j0 = *(const float4*)(rJ);
        r.j1 = *(const float4*)(rJ + 4);
    } else {
        r.i0 = r.i1 = r.j0 = r.j1 = float4{0.f, 0.f, 0.f, 0.f};
    }
    return r;
}

#define ACC(c, xv, yv)                          \
    sI[c]  += (xv); sJ[c] += (yv);              \
    sII[c]  = fmaf((xv), (xv), sII[c]);         \
    sJJ[c]  = fmaf((yv), (yv), sJJ[c]);         \
    sIJ[c]  = fmaf((xv), (yv), sIJ[c]);

#define UPD(c, nx, ny, ox, oy)                                  \
    sI[c]  += (nx) - (ox);                                      \
    sJ[c]  += (ny) - (oy);                                      \
    sII[c]  = fmaf((nx), (nx), fmaf(-(ox), (ox), sII[c]));      \
    sJJ[c]  = fmaf((ny), (ny), fmaf(-(oy), (oy), sJJ[c]));      \
    sIJ[c]  = fmaf((nx), (ny), fmaf(-(ox), (oy), sIJ[c]));

// NOTE: parameter must NOT be named `w` — the body's `.w` member accesses
// would be macro-substituted (round 4's compile failure).
#define ACC_ROWS(R)                              \
    ACC(0, R.i0.x, R.j0.x) ACC(1, R.i0.y, R.j0.y)\
    ACC(2, R.i0.z, R.j0.z) ACC(3, R.i0.w, R.j0.w)\
    ACC(4, R.i1.x, R.j1.x) ACC(5, R.i1.y, R.j1.y)\
    ACC(6, R.i1.z, R.j1.z) ACC(7, R.i1.w, R.j1.w)

#define UPD_ROWS(NR, OR)                                                  \
    UPD(0, NR.i0.x, NR.j0.x, OR.i0.x, OR.j0.x)                            \
    UPD(1, NR.i0.y, NR.j0.y, OR.i0.y, OR.j0.y)                            \
    UPD(2, NR.i0.z, NR.j0.z, OR.i0.z, OR.j0.z)                            \
    UPD(3, NR.i0.w, NR.j0.w, OR.i0.w, OR.j0.w)                            \
    UPD(4, NR.i1.x, NR.j1.x, OR.i1.x, OR.j1.x)                            \
    UPD(5, NR.i1.y, NR.j1.y, OR.i1.y, OR.j1.y)                            \
    UPD(6, NR.i1.z, NR.j1.z, OR.i1.z, OR.j1.z)                            \
    UPD(7, NR.i1.w, NR.j1.w, OR.i1.w, OR.j1.w)

// Horizontal 9-window over one quantity's 8 column-sums.
// Halo column-sums come from neighbor lanes; lane 0/63 masked = zero pad.
__device__ __forceinline__ void hwin(const float s[8], int lane, float w[8])
{
    float l[4], r[4];
    #pragma unroll
    for (int i = 0; i < 4; ++i) {
        float lv = __shfl_up(s[4 + i], 1, 64);
        float rv = __shfl_down(s[i],   1, 64);
        l[i] = (lane == 0)  ? 0.f : lv;
        r[i] = (lane == 63) ? 0.f : rv;
    }
    w[0] = ((l[0] + l[1]) + (l[2] + l[3])) +
           ((s[0] + s[1]) + (s[2] + s[3])) + s[4];
    w[1] = w[0] + s[5] - l[0];
    w[2] = w[1] + s[6] - l[1];
    w[3] = w[2] + s[7] - l[2];
    w[4] = w[3] + r[0] - l[3];
    w[5] = w[4] + r[1] - s[0];
    w[6] = w[5] + r[2] - s[1];
    w[7] = w[6] + r[3] - s[2];
}

// Fused single dispatch. Cross-block protocol uses ONLY atomic RMWs,
// which execute at the device coherent point (HW-verified primitive):
//   - slot publish: atomic EXCHANGE (swap_x2) — ack == global visibility
//     (round 10's relaxed STORE could retire into XCD-local L2: raced)
//   - counter: fetch_add residue trick (any initial value; each call adds
//     exactly NBLK, so exactly one block sees old%NBLK==NBLK-1; no init)
//   - slot read-back: fetch_add(slot, 0.0) — idempotent RMW READ at the
//     coherent point (round 10's relaxed LOAD could be served stale)
// No acq/rel fences anywhere: round 9 showed they emit L2 writeback/
// invalidate per block and destroy L2 locality chip-wide (2.3x).
__global__ __launch_bounds__(256) void ncc_band_kernel(
    const float* __restrict__ I, const float* __restrict__ J,
    double* __restrict__ slots, unsigned int* __restrict__ counter,
    float* __restrict__ out)
{
    const int lane = threadIdx.x & 63;
    const int wid  = threadIdx.x >> 6;
    // bijective XCD swizzle over 512 blocks (512 % 8 == 0):
    // XCD k gets a contiguous 256-band chunk (2 images ~ its 4MB L2).
    const int sblk = (blockIdx.x & 7) * (NBLK / 8) + (blockIdx.x >> 3);
    const int band = sblk * 4 + wid;              // 0..2047
    const int img  = band >> 7;                   // 128 bands / image
    const int y0   = (band & 127) * BAND;
    const int col0 = lane * 8;

    const float* Ib = I + (size_t)img * IMG * IMG;
    const float* Jb = J + (size_t)img * IMG * IMG;

    float sI[8], sJ[8], sII[8], sJJ[8], sIJ[8];
    #pragma unroll
    for (int c = 0; c < 8; ++c) { sI[c]=0.f; sJ[c]=0.f; sII[c]=0.f; sJJ[c]=0.f; sIJ[c]=0.f; }

    // ---- warm-up: rows y0-4 .. y0+4 (rolled; caps live registers) ----
    for (int r = -4; r <= 4; ++r) {
        Rows rr = load_rows(Ib, Jb, y0 + r, col0);
        ACC_ROWS(rr)
    }

    float local = 0.0f;

    // lean hpass: one shared transient, wI/wJ reused for Iv/Jv
    auto hpass = [&]() {
        float wI[8], wJ[8], t[8], cross[8];
        hwin(sI, lane, wI);
        hwin(sJ, lane, wJ);
        hwin(sIJ, lane, t);
        #pragma unroll
        for (int k = 0; k < 8; ++k)
            cross[k] = fmaxf(fmaf(-wI[k] * INV81, wJ[k], t[k]), EPS);
        hwin(sII, lane, t);
        #pragma unroll
        for (int k = 0; k < 8; ++k)
            wI[k] = fmaxf(fmaf(-wI[k] * INV81, wI[k], t[k]), EPS);   // Iv
        hwin(sJJ, lane, t);
        #pragma unroll
        for (int k = 0; k < 8; ++k)
            wJ[k] = fmaxf(fmaf(-wJ[k] * INV81, wJ[k], t[k]), EPS);   // Jv
        #pragma unroll
        for (int k = 0; k < 8; ++k)
            local += (cross[k] * cross[k]) * __builtin_amdgcn_rcpf(wI[k] * wJ[k]);
    };

    // ---- main loop: 4 output rows, transitions t=0..2
    //      (new = y0+5+t, old = y0-4+t), loads issued >=1 hpass ahead ----
    Rows nw0 = load_rows(Ib, Jb, y0 + 5, col0);
    Rows od0 = load_rows(Ib, Jb, y0 - 4, col0);
    Rows nw1 = load_rows(Ib, Jb, y0 + 6, col0);
    Rows od1 = load_rows(Ib, Jb, y0 - 3, col0);

    hpass();                               // row y0
    UPD_ROWS(nw0, od0)
    nw0 = load_rows(Ib, Jb, y0 + 7, col0);
    od0 = load_rows(Ib, Jb, y0 - 2, col0);
    hpass();                               // row y0+1
    UPD_ROWS(nw1, od1)
    hpass();                               // row y0+2
    UPD_ROWS(nw0, od0)
    hpass();                               // row y0+3

    // ---- wave reduction -> slot publish via atomic EXCHANGE ----
    #pragma unroll
    for (int off = 32; off > 0; off >>= 1)
        local += __shfl_down(local, off, 64);
    if (lane == 0) {
        double old = __hip_atomic_exchange(&slots[band], (double)local,
                                           __ATOMIC_RELAXED,
                                           __HIP_MEMORY_SCOPE_AGENT);
        asm volatile("" :: "v"(old));      // keep the returning RMW live
    }

    // each wave drains its own exchange's ack (RMW ack == coherent-point
    // completion), then block barrier -> all 4 slots globally current.
    asm volatile("s_waitcnt vmcnt(0)" ::: "memory");
    __syncthreads();

    __shared__ bool amLast;
    if (threadIdx.x == 0) {
        unsigned int old = __hip_atomic_fetch_add(
            counter, 1u, __ATOMIC_RELAXED, __HIP_MEMORY_SCOPE_AGENT);
        amLast = ((old & (NBLK - 1)) == NBLK - 1);
    }
    __syncthreads();

    // ---- last block reduces all slots via idempotent RMW reads ----
    if (amLast) {
        const int tid = threadIdx.x;
        double t = 0.0;
        #pragma unroll
        for (int i = 0; i < NBANDS / 256; ++i)
            t += __hip_atomic_fetch_add(&slots[tid + i * 256], 0.0,
                                        __ATOMIC_RELAXED,
                                        __HIP_MEMORY_SCOPE_AGENT);
        #pragma unroll
        for (int off = 32; off > 0; off >>= 1)
            t += __shfl_down(t, off, 64);

        __shared__ double wsum[4];
        if ((tid & 63) == 0) wsum[tid >> 6] = t;
        __syncthreads();
        if (tid == 0)
            out[0] = (float)(-(wsum[0] + wsum[1] + wsum[2] + wsum[3]) / NPIX);
    }
}

extern "C" void kernel_launch(void* const* d_in, const int* in_sizes, int n_in,
                              void* d_out, int out_size, void* d_ws, size_t ws_size,
                              hipStream_t stream)
{
    const float* I = (const float*)d_in[0];   // y_true
    const float* J = (const float*)d_in[1];   // y_pred
    float* out = (float*)d_out;
    double* slots = (double*)d_ws;                 // 2048 doubles
    unsigned int* counter = (unsigned int*)(slots + NBANDS);  // next 4 bytes

    // single dispatch: 512 blocks x 256 threads
    ncc_band_kernel<<<NBLK, 256, 0, stream>>>(I, J, slots, counter, out);
}

// Round 18
// 18.659 us; speedup vs baseline: 2.4506x; 1.0325x over previous
//
#include <hip/hip_runtime.h>

#define IMG    512
#define BAND   4            // output rows per wave
#define NBANDS 2048         // 16 images x 128 bands
#define NBLK   512          // 4 waves per block
#define NPIX   (16.0 * 512.0 * 512.0)
#define EPS    1e-5f
#define INV81  (1.0f / 81.0f)

struct Rows { float4 i0, i1, j0, j1; };

__device__ __forceinline__ Rows load_rows(const float* __restrict__ Ib,
                                          const float* __restrict__ Jb,
                                          int y, int col0)
{
    Rows r;
    if (y >= 0 && y < IMG) {          // wave-uniform (y uniform per wave)
        const float* rI = Ib + (size_t)y * IMG + col0;
        const float* rJ = Jb + (size_t)y * IMG + col0;
        r.i0 = *(const float4*)(rI);
        r.i1 = *(const float4*)(rI + 4);
        r.j0 = *(const float4*)(rJ);
        r.j1 = *(const float4*)(rJ + 4);
    } else {
        r.i0 = r.i1 = r.j0 = r.j1 = float4{0.f, 0.f, 0.f, 0.f};
    }
    return r;
}

#define ACC(c, xv, yv)                          \
    sI[c]  += (xv); sJ[c] += (yv);              \
    sII[c]  = fmaf((xv), (xv), sII[c]);         \
    sJJ[c]  = fmaf((yv), (yv), sJJ[c]);         \
    sIJ[c]  = fmaf((xv), (yv), sIJ[c]);

#define UPD(c, nx, ny, ox, oy)                                  \
    sI[c]  += (nx) - (ox);                                      \
    sJ[c]  += (ny) - (oy);                                      \
    sII[c]  = fmaf((nx), (nx), fmaf(-(ox), (ox), sII[c]));      \
    sJJ[c]  = fmaf((ny), (ny), fmaf(-(oy), (oy), sJJ[c]));      \
    sIJ[c]  = fmaf((nx), (ny), fmaf(-(ox), (oy), sIJ[c]));

// NOTE: parameter must NOT be named `w` — the body's `.w` member accesses
// would be macro-substituted (round 4's compile failure).
#define ACC_ROWS(R)                              \
    ACC(0, R.i0.x, R.j0.x) ACC(1, R.i0.y, R.j0.y)\
    ACC(2, R.i0.z, R.j0.z) ACC(3, R.i0.w, R.j0.w)\
    ACC(4, R.i1.x, R.j1.x) ACC(5, R.i1.y, R.j1.y)\
    ACC(6, R.i1.z, R.j1.z) ACC(7, R.i1.w, R.j1.w)

#define UPD_ROWS(NR, OR)                                                  \
    UPD(0, NR.i0.x, NR.j0.x, OR.i0.x, OR.j0.x)                            \
    UPD(1, NR.i0.y, NR.j0.y, OR.i0.y, OR.j0.y)                            \
    UPD(2, NR.i0.z, NR.j0.z, OR.i0.z, OR.j0.z)                            \
    UPD(3, NR.i0.w, NR.j0.w, OR.i0.w, OR.j0.w)                            \
    UPD(4, NR.i1.x, NR.j1.x, OR.i1.x, OR.j1.x)                            \
    UPD(5, NR.i1.y, NR.j1.y, OR.i1.y, OR.j1.y)                            \
    UPD(6, NR.i1.z, NR.j1.z, OR.i1.z, OR.j1.z)                            \
    UPD(7, NR.i1.w, NR.j1.w, OR.i1.w, OR.j1.w)

// Horizontal 9-window over one quantity's 8 column-sums.
// Halo column-sums from neighbor lanes via __shfl (PROVEN absmax-0 form;
// round 12's DPP wave_shr/shl produced wrong results on gfx950 — reverted).
// lane 0/63 masked to zero == image zero-padding.
__device__ __forceinline__ void hwin(const float s[8], int lane, float w[8])
{
    float l[4], r[4];
    #pragma unroll
    for (int i = 0; i < 4; ++i) {
        float lv = __shfl_up(s[4 + i], 1, 64);
        float rv = __shfl_down(s[i],   1, 64);
        l[i] = (lane == 0)  ? 0.f : lv;
        r[i] = (lane == 63) ? 0.f : rv;
    }
    w[0] = ((l[0] + l[1]) + (l[2] + l[3])) +
           ((s[0] + s[1]) + (s[2] + s[3])) + s[4];
    w[1] = w[0] + s[5] - l[0];
    w[2] = w[1] + s[6] - l[1];
    w[3] = w[2] + s[7] - l[2];
    w[4] = w[3] + r[0] - l[3];
    w[5] = w[4] + r[1] - s[0];
    w[6] = w[5] + r[2] - s[1];
    w[7] = w[6] + r[3] - s[2];
}

// Fused single dispatch; cross-block protocol = atomic RMWs only (round 11,
// passing): exchange publish, fetch_add residue counter, fetch_add(0.0)
// read-back. No acq/rel fences (round 9: L2 writeback/inv chip-wide, 2.3x).
//
// Register-for-latency restructure (this round): at 2048 waves we are
// pinned at 2 waves/SIMD, so up to 256 VGPR/wave are FREE. Warm-up is
// fully unrolled with a 4-issue front + 2-deep ping-pong; rows y0-4 and
// y0-3 are HELD in registers from warm-up to their UPD (kills 2 of 3
// re-reads); nw loads issue inside the warm-up tail so hpass #1 covers
// their latency. 13 row-loads/wave (was 15, ideal 12).
__global__ __launch_bounds__(256) void ncc_band_kernel(
    const float* __restrict__ I, const float* __restrict__ J,
    double* __restrict__ slots, unsigned int* __restrict__ counter,
    float* __restrict__ out)
{
    const int lane = threadIdx.x & 63;
    const int wid  = threadIdx.x >> 6;
    // bijective XCD swizzle over 512 blocks (512 % 8 == 0):
    // XCD k gets a contiguous 256-band chunk (2 images ~ its 4MB L2).
    const int sblk = (blockIdx.x & 7) * (NBLK / 8) + (blockIdx.x >> 3);
    const int band = sblk * 4 + wid;              // 0..2047
    const int img  = band >> 7;                   // 128 bands / image
    const int y0   = (band & 127) * BAND;
    const int col0 = lane * 8;

    const float* Ib = I + (size_t)img * IMG * IMG;
    const float* Jb = J + (size_t)img * IMG * IMG;

    float sI[8], sJ[8], sII[8], sJJ[8], sIJ[8];
    #pragma unroll
    for (int c = 0; c < 8; ++c) { sI[c]=0.f; sJ[c]=0.f; sII[c]=0.f; sJJ[c]=0.f; sIJ[c]=0.f; }

    // ---- warm-up rows y0-4..y0+4: 4 loads in flight up front, then
    //      2-deep ping-pong. od0/od1 stay live until their UPDs. ----
    Rows od0 = load_rows(Ib, Jb, y0 - 4, col0);   // held
    Rows od1 = load_rows(Ib, Jb, y0 - 3, col0);   // held
    Rows A   = load_rows(Ib, Jb, y0 - 2, col0);
    Rows B   = load_rows(Ib, Jb, y0 - 1, col0);

    ACC_ROWS(od0)
    ACC_ROWS(od1)
    ACC_ROWS(A)  A = load_rows(Ib, Jb, y0 + 0, col0);
    ACC_ROWS(B)  B = load_rows(Ib, Jb, y0 + 1, col0);
    ACC_ROWS(A)  A = load_rows(Ib, Jb, y0 + 2, col0);
    ACC_ROWS(B)  B = load_rows(Ib, Jb, y0 + 3, col0);
    ACC_ROWS(A)  A = load_rows(Ib, Jb, y0 + 4, col0);
    ACC_ROWS(B)  B = load_rows(Ib, Jb, y0 + 5, col0);   // nw0
    ACC_ROWS(A)  A = load_rows(Ib, Jb, y0 + 6, col0);   // nw1
    // sums now cover rows y0-4..y0+4; B=row y0+5, A=row y0+6 in flight.

    float local = 0.0f;

    // lean hpass: one shared transient, wI/wJ reused for Iv/Jv
    auto hpass = [&]() {
        float wI[8], wJ[8], t[8], cross[8];
        hwin(sI, lane, wI);
        hwin(sJ, lane, wJ);
        hwin(sIJ, lane, t);
        #pragma unroll
        for (int k = 0; k < 8; ++k)
            cross[k] = fmaxf(fmaf(-wI[k] * INV81, wJ[k], t[k]), EPS);
        hwin(sII, lane, t);
        #pragma unroll
        for (int k = 0; k < 8; ++k)
            wI[k] = fmaxf(fmaf(-wI[k] * INV81, wI[k], t[k]), EPS);   // Iv
        hwin(sJJ, lane, t);
        #pragma unroll
        for (int k = 0; k < 8; ++k)
            wJ[k] = fmaxf(fmaf(-wJ[k] * INV81, wJ[k], t[k]), EPS);   // Jv
        #pragma unroll
        for (int k = 0; k < 8; ++k)
            local += (cross[k] * cross[k]) * __builtin_amdgcn_rcpf(wI[k] * wJ[k]);
    };

    hpass();                               // row y0      (covers B,A loads)
    UPD_ROWS(B, od0)                       // +y0+5, -y0-4 (od0 freed)
    B = load_rows(Ib, Jb, y0 + 7, col0);   // nw2
    hpass();                               // row y0+1
    UPD_ROWS(A, od1)                       // +y0+6, -y0-3 (od1 freed)
    A = load_rows(Ib, Jb, y0 - 2, col0);   // od2 re-read (L2-resident)
    hpass();                               // row y0+2
    UPD_ROWS(B, A)                         // +y0+7, -y0-2
    hpass();                               // row y0+3

    // ---- wave reduction -> slot publish via atomic EXCHANGE ----
    #pragma unroll
    for (int off = 32; off > 0; off >>= 1)
        local += __shfl_down(local, off, 64);
    if (lane == 0) {
        double old = __hip_atomic_exchange(&slots[band], (double)local,
                                           __ATOMIC_RELAXED,
                                           __HIP_MEMORY_SCOPE_AGENT);
        asm volatile("" :: "v"(old));      // keep the returning RMW live
    }

    // each wave drains its own exchange's ack (RMW ack == coherent-point
    // completion), then block barrier -> all 4 slots globally current.
    asm volatile("s_waitcnt vmcnt(0)" ::: "memory");
    __syncthreads();

    __shared__ bool amLast;
    if (threadIdx.x == 0) {
        unsigned int old = __hip_atomic_fetch_add(
            counter, 1u, __ATOMIC_RELAXED, __HIP_MEMORY_SCOPE_AGENT);
        amLast = ((old & (NBLK - 1)) == NBLK - 1);
    }
    __syncthreads();

    // ---- last block reduces all slots via idempotent RMW reads ----
    if (amLast) {
        const int tid = threadIdx.x;
        double t = 0.0;
        #pragma unroll
        for (int i = 0; i < NBANDS / 256; ++i)
            t += __hip_atomic_fetch_add(&slots[tid + i * 256], 0.0,
                                        __ATOMIC_RELAXED,
                                        __HIP_MEMORY_SCOPE_AGENT);
        #pragma unroll
        for (int off = 32; off > 0; off >>= 1)
            t += __shfl_down(t, off, 64);

        __shared__ double wsum[4];
        if ((tid & 63) == 0) wsum[tid >> 6] = t;
        __syncthreads();
        if (tid == 0)
            out[0] = (float)(-(wsum[0] + wsum[1] + wsum[2] + wsum[3]) / NPIX);
    }
}

extern "C" void kernel_launch(void* const* d_in, const int* in_sizes, int n_in,
                              void* d_out, int out_size, void* d_ws, size_t ws_size,
                              hipStream_t stream)
{
    const float* I = (const float*)d_in[0];   // y_true
    const float* J = (const float*)d_in[1];   // y_pred
    float* out = (float*)d_out;
    double* slots = (double*)d_ws;                 // 2048 doubles
    unsigned int* counter = (unsigned int*)(slots + NBANDS);  // next 4 bytes

    // single dispatch: 512 blocks x 256 threads
    ncc_band_kernel<<<NBLK, 256, 0, stream>>>(I, J, slots, counter, out);
}